// Round 2
// baseline (695.817 us; speedup 1.0000x reference)
//
#include <hip/hip_runtime.h>
#include <stdint.h>

// MultiHeadedAttentionSANM: B=8,T=1024,F=1024,H=16,Dk=64,KERNEL=11
// Pipeline: cvt->bf16 | GEMM1 qkv (v written transposed) | maskbits | fsmn->d_out |
//           attn (swapped-QK^T, LDS-free) | GEMM2(+bias+fsmn)->d_out
// ws layout (bytes): hsb[0,16M) wqkvb[16M,22M) woutb[22M,24M) q[24M,40M) k[40M,56M)
//                    vt[56M,72M) ctx[72M,88M); maskbits reuses hsb region after GEMM1.
// total ws needed = 92,274,688 bytes

typedef uint16_t u16;
typedef float f32x4 __attribute__((ext_vector_type(4)));
typedef __bf16 bf16x8 __attribute__((ext_vector_type(8)));
typedef __bf16 bf16x2 __attribute__((ext_vector_type(2)));

__device__ __forceinline__ u16 f2bf(float f) {
    union { float f; uint32_t u; } c; c.f = f;
    uint32_t u = c.u;
    return (u16)((u + 0x7fffu + ((u >> 16) & 1u)) >> 16);
}
__device__ __forceinline__ float bf2f(u16 h) {
    union { uint32_t u; float f; } c; c.u = ((uint32_t)h) << 16;
    return c.f;
}
__device__ __forceinline__ uint32_t pack_bf16(float a, float b) {
    bf16x2 t; t[0] = (__bf16)a; t[1] = (__bf16)b;
    union { bf16x2 v; uint32_t u; } c; c.v = t; return c.u;
}

// ---------------- fp32 -> bf16 convert ----------------
__global__ __launch_bounds__(256) void cvt_f32_bf16(const float* __restrict__ src,
                                                    u16* __restrict__ dst, int n) {
    int i = (blockIdx.x * 256 + threadIdx.x) * 4;
    if (i >= n) return;
    float4 v = *reinterpret_cast<const float4*>(src + i);
    ushort4 o;
    o.x = f2bf(v.x); o.y = f2bf(v.y); o.z = f2bf(v.z); o.w = f2bf(v.w);
    *reinterpret_cast<ushort4*>(dst + i) = o;
}

// ---------------- mask -> bitmask (8 batches x 32 u32) ----------------
__global__ void maskbits_kernel(const int* __restrict__ mask, uint32_t* __restrict__ mb) {
    int i = threadIdx.x;           // 0..255
    int b = i >> 5, c = i & 31;
    uint32_t u = 0;
    for (int j = 0; j < 32; ++j)
        u |= (mask[(b << 10) + c * 32 + j] ? 1u : 0u) << j;
    mb[i] = u;
}

// ---------------- 128x128 bf16 MFMA GEMM, B given as [N,K] (B^T form) ----------------
// MODE 0: epilogue scatters qkv -> q(x0.125)/k natural [B,H,T,64], v TRANSPOSED [B,H,64,T]
// MODE 1: out[row,col] += acc + bias[col]   (out already holds fsmn memory)
template<int MODE>
__global__ __launch_bounds__(256) void gemm128(
    const u16* __restrict__ A, const u16* __restrict__ Bw, int M, int N, int K,
    int ntiles_n, const float* __restrict__ bias,
    u16* __restrict__ qo, u16* __restrict__ ko, u16* __restrict__ vo,
    float* __restrict__ out)
{
    __shared__ u16 As[128 * 32];
    __shared__ u16 Bs[128 * 32];
    const int t = threadIdx.x;
    const int lane = t & 63;
    const int wave = t >> 6;
    const int wr = wave >> 1, wc = wave & 1;
    const int lr = lane & 15, lq = lane >> 4;
    const int mt = blockIdx.x / ntiles_n;
    const int nt = blockIdx.x % ntiles_n;
    const int m0 = mt * 128, n0 = nt * 128;

    const u16* ag = A + (size_t)m0 * K;
    const u16* bg = Bw + (size_t)n0 * K;

    f32x4 acc[4][4];
#pragma unroll
    for (int i = 0; i < 4; ++i)
#pragma unroll
        for (int j = 0; j < 4; ++j) acc[i][j] = (f32x4){0.f, 0.f, 0.f, 0.f};

    for (int k0 = 0; k0 < K; k0 += 32) {
#pragma unroll
        for (int i = 0; i < 2; ++i) {
            int c = i * 256 + t;
            const u16* gA = ag + (size_t)(c >> 2) * K + k0 + (c & 3) * 8;
            const u16* gB = bg + (size_t)(c >> 2) * K + k0 + (c & 3) * 8;
            __builtin_amdgcn_global_load_lds(
                (const __attribute__((address_space(1))) void*)gA,
                (__attribute__((address_space(3))) void*)(As + i * 2048 + wave * 512),
                16, 0, 0);
            __builtin_amdgcn_global_load_lds(
                (const __attribute__((address_space(1))) void*)gB,
                (__attribute__((address_space(3))) void*)(Bs + i * 2048 + wave * 512),
                16, 0, 0);
        }
        __syncthreads();
        bf16x8 af[4], bf[4];
#pragma unroll
        for (int m = 0; m < 4; ++m)
            af[m] = *reinterpret_cast<const bf16x8*>(As + (wr * 64 + m * 16 + lr) * 32 + lq * 8);
#pragma unroll
        for (int n = 0; n < 4; ++n)
            bf[n] = *reinterpret_cast<const bf16x8*>(Bs + (wc * 64 + n * 16 + lr) * 32 + lq * 8);
#pragma unroll
        for (int m = 0; m < 4; ++m)
#pragma unroll
            for (int n = 0; n < 4; ++n)
                acc[m][n] = __builtin_amdgcn_mfma_f32_16x16x32_bf16(af[m], bf[n], acc[m][n], 0, 0, 0);
        __syncthreads();
    }

#pragma unroll
    for (int m = 0; m < 4; ++m) {
        int row = m0 + wr * 64 + m * 16 + lq * 4;
#pragma unroll
        for (int n = 0; n < 4; ++n) {
            int col = n0 + wc * 64 + n * 16 + lr;
            float bv = bias[col];
#pragma unroll
            for (int r = 0; r < 4; ++r) {
                float val = acc[m][n][r] + bv;
                int rr = row + r;
                if (MODE == 0) {
                    int part = col >> 10;
                    int cc = col & 1023;
                    int h = cc >> 6, d = cc & 63;
                    int b = rr >> 10, tt = rr & 1023;
                    size_t bh = (size_t)(b * 16 + h);
                    if (part == 0)      qo[((bh << 10) + tt) * 64 + d] = f2bf(val * 0.125f);
                    else if (part == 1) ko[((bh << 10) + tt) * 64 + d] = f2bf(val);
                    else                vo[(bh << 16) + (size_t)d * 1024 + tt] = f2bf(val);
                } else {
                    size_t o = (size_t)rr * N + col;
                    out[o] += val;
                }
            }
        }
    }
}

// ---------------- FSMN depthwise conv, reads v^T, writes fp32 into d_out ----------------
__global__ __launch_bounds__(256) void fsmn_kernel(const u16* __restrict__ vt,
                                                   const int* __restrict__ mask,
                                                   const float* __restrict__ kern,
                                                   float* __restrict__ out)
{
    int idx = blockIdx.x * 256 + threadIdx.x;     // [b,t,c]
    int c = idx & 1023;
    int tt = (idx >> 10) & 1023;
    int b = idx >> 20;
    const int* mrow = mask + (b << 10);
    float mf = (float)mrow[tt];
    const u16* row = vt + (((size_t)(b * 16 + (c >> 6))) << 16) + (size_t)(c & 63) * 1024;
    const float* kc = kern + c * 11;
    float acc = 0.f;
#pragma unroll
    for (int j = 0; j < 11; ++j) {
        int ts = tt + j - 5;
        if (ts >= 0 && ts < 1024)
            acc += kc[j] * (bf2f(row[ts]) * (float)mrow[ts]);
    }
    float vm = bf2f(row[tt]) * mf;
    out[idx] = (acc + vm) * mf;
}

// ---------------- attention v2: swapped QK^T, in-register softmax, LDS-free ----------------
// block = 256 thr = 4 waves; wave owns 32 q-rows; grid = bh(128) x qchunk(8)
// S^T = mfma(A=K[16k x 64d], B=Q^T[64d x 16q]): lane holds q=lane&15, keys 4*lq+r
// PV  = mfma(A=P[16q x 32k], B=V^T frag from vt[bh][d][t])
__global__ __launch_bounds__(256, 3) void attn_v2(const u16* __restrict__ qg,
                                                  const u16* __restrict__ kg,
                                                  const u16* __restrict__ vtg,
                                                  const uint32_t* __restrict__ mbits,
                                                  u16* __restrict__ ctx)
{
    const int t = threadIdx.x;
    const int lane = t & 63;
    const int w = t >> 6;
    const int lr = lane & 15, lq = lane >> 4;
    const int qc = blockIdx.x & 7;
    const int bh = blockIdx.x >> 3;
    const int b = bh >> 4, h = bh & 15;
    const size_t base = (size_t)bh << 16;
    const u16* kb = kg + base;
    const u16* vb = vtg + base;     // [64][1024]
    const int q0 = qc * 128 + w * 32;

    // Q fragments (B-operand of swapped QK^T): lane holds Q[q=lr][32*kk+8*lq+e]
    bf16x8 qf[2][2];
#pragma unroll
    for (int qt = 0; qt < 2; ++qt)
#pragma unroll
        for (int kk = 0; kk < 2; ++kk)
            qf[qt][kk] = *reinterpret_cast<const bf16x8*>(
                qg + base + (size_t)(q0 + qt * 16 + lr) * 64 + kk * 32 + lq * 8);

    f32x4 oacc[2][4];
    float m_[2] = {-1e30f, -1e30f}, l_[2] = {0.f, 0.f};
#pragma unroll
    for (int qt = 0; qt < 2; ++qt)
#pragma unroll
        for (int dt = 0; dt < 4; ++dt) oacc[qt][dt] = (f32x4){0.f, 0.f, 0.f, 0.f};

    const uint32_t* mrow = mbits + b * 32;

    // prefetched K/V fragments
    bf16x8 kf[2][2], vf[4];
#pragma unroll
    for (int kt = 0; kt < 2; ++kt)
#pragma unroll
        for (int kk = 0; kk < 2; ++kk)
            kf[kt][kk] = *reinterpret_cast<const bf16x8*>(
                kb + (size_t)(kt * 16 + lr) * 64 + kk * 32 + lq * 8);
#pragma unroll
    for (int dt = 0; dt < 4; ++dt)
        vf[dt] = *reinterpret_cast<const bf16x8*>(vb + (size_t)(dt * 16 + lr) * 1024 + lq * 8);

    for (int it = 0; it < 32; ++it) {
        // prefetch next iteration (clamped; redundant reload on last iter)
        const int k1 = (it < 31 ? it + 1 : 31) * 32;
        bf16x8 kf_n[2][2], vf_n[4];
#pragma unroll
        for (int kt = 0; kt < 2; ++kt)
#pragma unroll
            for (int kk = 0; kk < 2; ++kk)
                kf_n[kt][kk] = *reinterpret_cast<const bf16x8*>(
                    kb + (size_t)(k1 + kt * 16 + lr) * 64 + kk * 32 + lq * 8);
#pragma unroll
        for (int dt = 0; dt < 4; ++dt)
            vf_n[dt] = *reinterpret_cast<const bf16x8*>(
                vb + (size_t)(dt * 16 + lr) * 1024 + k1 + lq * 8);

        const uint32_t mbit = mrow[it];
        f32x4 ma[2];
#pragma unroll
        for (int kt = 0; kt < 2; ++kt)
#pragma unroll
            for (int r = 0; r < 4; ++r)
                ma[kt][r] = ((mbit >> (kt * 16 + lq * 4 + r)) & 1u) ? 0.f : -3e38f;

        uint32_t pk[2][2][2];
        float alpha[2];
#pragma unroll
        for (int qt = 0; qt < 2; ++qt) {
            f32x4 s0 = (f32x4){0.f, 0.f, 0.f, 0.f};
            f32x4 s1 = (f32x4){0.f, 0.f, 0.f, 0.f};
            s0 = __builtin_amdgcn_mfma_f32_16x16x32_bf16(kf[0][0], qf[qt][0], s0, 0, 0, 0);
            s0 = __builtin_amdgcn_mfma_f32_16x16x32_bf16(kf[0][1], qf[qt][1], s0, 0, 0, 0);
            s1 = __builtin_amdgcn_mfma_f32_16x16x32_bf16(kf[1][0], qf[qt][0], s1, 0, 0, 0);
            s1 = __builtin_amdgcn_mfma_f32_16x16x32_bf16(kf[1][1], qf[qt][1], s1, 0, 0, 0);
            s0 += ma[0]; s1 += ma[1];
            float mx = fmaxf(fmaxf(fmaxf(s0[0], s0[1]), fmaxf(s0[2], s0[3])),
                             fmaxf(fmaxf(s1[0], s1[1]), fmaxf(s1[2], s1[3])));
            mx = fmaxf(mx, __shfl_xor(mx, 16, 64));
            mx = fmaxf(mx, __shfl_xor(mx, 32, 64));
            float mn = fmaxf(m_[qt], mx);
            float al = __expf(m_[qt] - mn);
            m_[qt] = mn;
            float p0 = __expf(s0[0] - mn), p1 = __expf(s0[1] - mn);
            float p2 = __expf(s0[2] - mn), p3 = __expf(s0[3] - mn);
            float p4 = __expf(s1[0] - mn), p5 = __expf(s1[1] - mn);
            float p6 = __expf(s1[2] - mn), p7 = __expf(s1[3] - mn);
            float rs = ((p0 + p1) + (p2 + p3)) + ((p4 + p5) + (p6 + p7));
            rs += __shfl_xor(rs, 16, 64);
            rs += __shfl_xor(rs, 32, 64);
            l_[qt] = l_[qt] * al + rs;
            alpha[qt] = al;
            pk[qt][0][0] = pack_bf16(p0, p1); pk[qt][0][1] = pack_bf16(p2, p3);
            pk[qt][1][0] = pack_bf16(p4, p5); pk[qt][1][1] = pack_bf16(p6, p7);
        }

        // O rescale: acc row q' = 4*lq + r needs alpha of lane q'
#pragma unroll
        for (int qt = 0; qt < 2; ++qt) {
            float a0 = __shfl(alpha[qt], 4 * lq + 0, 64);
            float a1 = __shfl(alpha[qt], 4 * lq + 1, 64);
            float a2 = __shfl(alpha[qt], 4 * lq + 2, 64);
            float a3 = __shfl(alpha[qt], 4 * lq + 3, 64);
#pragma unroll
            for (int dt = 0; dt < 4; ++dt) {
                f32x4 o = oacc[qt][dt];
                o[0] *= a0; o[1] *= a1; o[2] *= a2; o[3] *= a3;
                oacc[qt][dt] = o;
            }
        }

        // redistribute P^T -> A-operand fragments, then PV
        const int srcA = lr + ((lq & 1) << 5);
        const int srcB = srcA + 16;
        const bool selA = (lq < 2);
#pragma unroll
        for (int qt = 0; qt < 2; ++qt) {
            int a0 = __shfl((int)pk[qt][0][0], srcA, 64);
            int a1 = __shfl((int)pk[qt][0][1], srcA, 64);
            int a2 = __shfl((int)pk[qt][0][0], srcB, 64);
            int a3 = __shfl((int)pk[qt][0][1], srcB, 64);
            int b0 = __shfl((int)pk[qt][1][0], srcA, 64);
            int b1 = __shfl((int)pk[qt][1][1], srcA, 64);
            int b2 = __shfl((int)pk[qt][1][0], srcB, 64);
            int b3 = __shfl((int)pk[qt][1][1], srcB, 64);
            union { uint32_t u[4]; bf16x8 v; } afu;
            afu.u[0] = (uint32_t)(selA ? a0 : b0);
            afu.u[1] = (uint32_t)(selA ? a1 : b1);
            afu.u[2] = (uint32_t)(selA ? a2 : b2);
            afu.u[3] = (uint32_t)(selA ? a3 : b3);
#pragma unroll
            for (int dt = 0; dt < 4; ++dt)
                oacc[qt][dt] = __builtin_amdgcn_mfma_f32_16x16x32_bf16(afu.v, vf[dt], oacc[qt][dt], 0, 0, 0);
        }

        // rotate prefetch
#pragma unroll
        for (int kt = 0; kt < 2; ++kt)
#pragma unroll
            for (int kk = 0; kk < 2; ++kk) kf[kt][kk] = kf_n[kt][kk];
#pragma unroll
        for (int dt = 0; dt < 4; ++dt) vf[dt] = vf_n[dt];
    }

    // epilogue: lane holds O[q'=4lq+r][d=16dt+lr]
#pragma unroll
    for (int qt = 0; qt < 2; ++qt) {
        float linv = 1.f / l_[qt];
        float li0 = __shfl(linv, 4 * lq + 0, 64);
        float li1 = __shfl(linv, 4 * lq + 1, 64);
        float li2 = __shfl(linv, 4 * lq + 2, 64);
        float li3 = __shfl(linv, 4 * lq + 3, 64);
        int trow = q0 + qt * 16 + lq * 4;
#pragma unroll
        for (int dt = 0; dt < 4; ++dt) {
            f32x4 o = oacc[qt][dt];
            size_t col = (size_t)h * 64 + dt * 16 + lr;
            ctx[((size_t)(b << 10) + trow + 0) * 1024 + col] = f2bf(o[0] * li0);
            ctx[((size_t)(b << 10) + trow + 1) * 1024 + col] = f2bf(o[1] * li1);
            ctx[((size_t)(b << 10) + trow + 2) * 1024 + col] = f2bf(o[2] * li2);
            ctx[((size_t)(b << 10) + trow + 3) * 1024 + col] = f2bf(o[3] * li3);
        }
    }
}

extern "C" void kernel_launch(void* const* d_in, const int* in_sizes, int n_in,
                              void* d_out, int out_size, void* d_ws, size_t ws_size,
                              hipStream_t stream)
{
    (void)in_sizes; (void)n_in; (void)out_size; (void)ws_size;
    const float* hs   = (const float*)d_in[0];
    const int*   mask = (const int*)d_in[1];
    const float* Wqkv = (const float*)d_in[2];
    const float* bqkv = (const float*)d_in[3];
    const float* Wout = (const float*)d_in[4];
    const float* bout = (const float*)d_in[5];
    const float* fk   = (const float*)d_in[6];
    float* out = (float*)d_out;

    char* ws = (char*)d_ws;
    u16* hsb   = (u16*)(ws);                 // dead after gemm1; tail reused for maskbits
    u16* wqkvb = (u16*)(ws + 16777216);
    u16* woutb = (u16*)(ws + 23068672);
    u16* qb    = (u16*)(ws + 25165824);      // [B,H,T,64]
    u16* kb    = (u16*)(ws + 41943040);      // [B,H,T,64]
    u16* vtb   = (u16*)(ws + 58720256);      // [B,H,64,T]
    u16* ctxb  = (u16*)(ws + 75497472);      // [B,T,1024]
    uint32_t* mbits = (uint32_t*)ws;         // 1 KB, reuses hsb region after gemm1

    cvt_f32_bf16<<<8192, 256, 0, stream>>>(hs,   hsb,   8388608);
    cvt_f32_bf16<<<3072, 256, 0, stream>>>(Wqkv, wqkvb, 3145728);
    cvt_f32_bf16<<<1024, 256, 0, stream>>>(Wout, woutb, 1048576);

    gemm128<0><<<64 * 24, 256, 0, stream>>>(hsb, wqkvb, 8192, 3072, 1024, 24,
                                            bqkv, qb, kb, vtb, nullptr);
    maskbits_kernel<<<1, 256, 0, stream>>>(mask, mbits);
    fsmn_kernel<<<32768, 256, 0, stream>>>(vtb, mask, fk, out);
    attn_v2<<<1024, 256, 0, stream>>>(qb, kb, vtb, mbits, ctxb);
    gemm128<1><<<64 * 8, 256, 0, stream>>>(ctxb, woutb, 8192, 1024, 1024, 8,
                                           bout, nullptr, nullptr, nullptr, out);
}

// Round 3
// 311.105 us; speedup vs baseline: 2.2366x; 2.2366x over previous
//
#include <hip/hip_runtime.h>
#include <stdint.h>

// MultiHeadedAttentionSANM: B=8,T=1024,F=1024,H=16,Dk=64,KERNEL=11
// Pipeline: cvt->bf16 | GEMM1 qkv (v written transposed) | maskbits+ktT | fsmn->d_out |
//           attn (swapped-QK^T, LDS-free) | GEMM2(+bias+fsmn)->d_out
// ws layout (bytes): hsb[0,16M) wqkvb[16M,22M) woutb[22M,24M) q[24M,40M) k[40M,56M)
//                    vt[56M,72M) ctx[72M,88M)
// hsb region is dead after GEMM1; mbits (1KB @ +0) and ktT (45KB @ +4096) reuse it.
// total ws needed = 92,274,688 bytes

typedef uint16_t u16;
typedef float f32x4 __attribute__((ext_vector_type(4)));
typedef __bf16 bf16x8 __attribute__((ext_vector_type(8)));
typedef __bf16 bf16x2 __attribute__((ext_vector_type(2)));
typedef u16 u16x8 __attribute__((ext_vector_type(8)));

__device__ __forceinline__ u16 f2bf(float f) {
    union { float f; uint32_t u; } c; c.f = f;
    uint32_t u = c.u;
    return (u16)((u + 0x7fffu + ((u >> 16) & 1u)) >> 16);
}
__device__ __forceinline__ float bf2f(u16 h) {
    union { uint32_t u; float f; } c; c.u = ((uint32_t)h) << 16;
    return c.f;
}
__device__ __forceinline__ uint32_t pack_bf16(float a, float b) {
    bf16x2 t; t[0] = (__bf16)a; t[1] = (__bf16)b;
    union { bf16x2 v; uint32_t u; } c; c.v = t; return c.u;
}

// ---------------- fp32 -> bf16 convert ----------------
__global__ __launch_bounds__(256) void cvt_f32_bf16(const float* __restrict__ src,
                                                    u16* __restrict__ dst, int n) {
    int i = (blockIdx.x * 256 + threadIdx.x) * 4;
    if (i >= n) return;
    float4 v = *reinterpret_cast<const float4*>(src + i);
    ushort4 o;
    o.x = f2bf(v.x); o.y = f2bf(v.y); o.z = f2bf(v.z); o.w = f2bf(v.w);
    *reinterpret_cast<ushort4*>(dst + i) = o;
}

// ---------------- mask -> bitmask (8 batches x 32 u32) ----------------
__global__ void maskbits_kernel(const int* __restrict__ mask, uint32_t* __restrict__ mb) {
    int i = threadIdx.x;           // 0..255
    int b = i >> 5, c = i & 31;
    uint32_t u = 0;
    for (int j = 0; j < 32; ++j)
        u |= (mask[(b << 10) + c * 32 + j] ? 1u : 0u) << j;
    mb[i] = u;
}

// ---------------- fsmn kernel transpose [1024][11] -> [11][1024] ----------------
__global__ __launch_bounds__(256) void fsmn_kt(const float* __restrict__ fk,
                                               float* __restrict__ kt) {
    int idx = blockIdx.x * 256 + threadIdx.x;
    if (idx < 11 * 1024) {
        int j = idx >> 10, c = idx & 1023;
        kt[idx] = fk[c * 11 + j];
    }
}

// ---------------- 128x128 bf16 MFMA GEMM, B given as [N,K] (B^T form) ----------------
// MODE 0: epilogue scatters qkv -> q(x0.125)/k natural [B,H,T,64], v TRANSPOSED [B,H,64,T]
// MODE 1: out[row,col] += acc + bias[col]   (out already holds fsmn memory)
template<int MODE>
__global__ __launch_bounds__(256) void gemm128(
    const u16* __restrict__ A, const u16* __restrict__ Bw, int M, int N, int K,
    int ntiles_n, const float* __restrict__ bias,
    u16* __restrict__ qo, u16* __restrict__ ko, u16* __restrict__ vo,
    float* __restrict__ out)
{
    __shared__ u16 As[128 * 32];
    __shared__ u16 Bs[128 * 32];
    const int t = threadIdx.x;
    const int lane = t & 63;
    const int wave = t >> 6;
    const int wr = wave >> 1, wc = wave & 1;
    const int lr = lane & 15, lq = lane >> 4;
    // bijective XCD swizzle (grid % 8 == 0 for both call sites)
    const int nwg = gridDim.x;
    const int cpx = nwg >> 3;
    const int bid = (blockIdx.x & 7) * cpx + (blockIdx.x >> 3);
    const int mt = bid / ntiles_n;
    const int nt = bid % ntiles_n;
    const int m0 = mt * 128, n0 = nt * 128;

    const u16* ag = A + (size_t)m0 * K;
    const u16* bg = Bw + (size_t)n0 * K;

    f32x4 acc[4][4];
#pragma unroll
    for (int i = 0; i < 4; ++i)
#pragma unroll
        for (int j = 0; j < 4; ++j) acc[i][j] = (f32x4){0.f, 0.f, 0.f, 0.f};

    for (int k0 = 0; k0 < K; k0 += 32) {
#pragma unroll
        for (int i = 0; i < 2; ++i) {
            int c = i * 256 + t;
            const u16* gA = ag + (size_t)(c >> 2) * K + k0 + (c & 3) * 8;
            const u16* gB = bg + (size_t)(c >> 2) * K + k0 + (c & 3) * 8;
            __builtin_amdgcn_global_load_lds(
                (const __attribute__((address_space(1))) void*)gA,
                (__attribute__((address_space(3))) void*)(As + i * 2048 + wave * 512),
                16, 0, 0);
            __builtin_amdgcn_global_load_lds(
                (const __attribute__((address_space(1))) void*)gB,
                (__attribute__((address_space(3))) void*)(Bs + i * 2048 + wave * 512),
                16, 0, 0);
        }
        __syncthreads();
        bf16x8 af[4], bf[4];
#pragma unroll
        for (int m = 0; m < 4; ++m)
            af[m] = *reinterpret_cast<const bf16x8*>(As + (wr * 64 + m * 16 + lr) * 32 + lq * 8);
#pragma unroll
        for (int n = 0; n < 4; ++n)
            bf[n] = *reinterpret_cast<const bf16x8*>(Bs + (wc * 64 + n * 16 + lr) * 32 + lq * 8);
#pragma unroll
        for (int m = 0; m < 4; ++m)
#pragma unroll
            for (int n = 0; n < 4; ++n)
                acc[m][n] = __builtin_amdgcn_mfma_f32_16x16x32_bf16(af[m], bf[n], acc[m][n], 0, 0, 0);
        __syncthreads();
    }

#pragma unroll
    for (int m = 0; m < 4; ++m) {
        int row = m0 + wr * 64 + m * 16 + lq * 4;
#pragma unroll
        for (int n = 0; n < 4; ++n) {
            int col = n0 + wc * 64 + n * 16 + lr;
            float bv = bias[col];
#pragma unroll
            for (int r = 0; r < 4; ++r) {
                float val = acc[m][n][r] + bv;
                int rr = row + r;
                if (MODE == 0) {
                    int part = col >> 10;
                    int cc = col & 1023;
                    int h = cc >> 6, d = cc & 63;
                    int b = rr >> 10, tt = rr & 1023;
                    size_t bh = (size_t)(b * 16 + h);
                    if (part == 0)      qo[((bh << 10) + tt) * 64 + d] = f2bf(val * 0.125f);
                    else if (part == 1) ko[((bh << 10) + tt) * 64 + d] = f2bf(val);
                    else                vo[(bh << 16) + (size_t)d * 1024 + tt] = f2bf(val);
                } else {
                    size_t o = (size_t)rr * N + col;
                    out[o] += val;
                }
            }
        }
    }
}

// ---------------- FSMN v3: LDS-transpose, reads vt coalesced, writes d_out coalesced ----
// block = (bh, 128-t chunk); grid = 128*8 = 1024
__global__ __launch_bounds__(256) void fsmn_v3(const u16* __restrict__ vt,
                                               const int* __restrict__ mask,
                                               const float* __restrict__ kt,
                                               float* __restrict__ out)
{
    __shared__ float vs[64][147];   // [d][i], i=0 <-> t0-8, premultiplied by mask
    __shared__ float ms[144];
    const int tid = threadIdx.x;
    const int tc = blockIdx.x & 7;
    const int bh = blockIdx.x >> 3;
    const int b = bh >> 4, h = bh & 15;
    const int t0 = tc * 128;
    const u16* vrow = vt + ((size_t)bh << 16);
    const int* mrow = mask + (b << 10);

    if (tid < 144) {
        int tt = t0 - 8 + tid;
        ms[tid] = (tt >= 0 && tt < 1024) ? (float)mrow[tt] : 0.f;
    }
    // stage vs: 64 rows x 18 chunks of 8; chunks are 8-aligned so all-in or all-out
    const int sd = tid >> 2;
    const int ci0 = tid & 3;
#pragma unroll
    for (int it = 0; it < 5; ++it) {
        int ci = ci0 + it * 4;
        if (ci < 18) {
            int tbase = t0 - 8 + ci * 8;
            if (tbase >= 0 && tbase < 1024) {
                u16x8 v8 = *reinterpret_cast<const u16x8*>(vrow + (size_t)sd * 1024 + tbase);
#pragma unroll
                for (int j = 0; j < 8; ++j)
                    vs[sd][ci * 8 + j] = bf2f((u16)v8[j]) * (float)mrow[tbase + j];
            } else {
#pragma unroll
                for (int j = 0; j < 8; ++j) vs[sd][ci * 8 + j] = 0.f;
            }
        }
    }
    __syncthreads();

    const int dd = tid & 63;
    const int tg = tid >> 6;            // 0..3, each covers 32 t
    const int c = h * 64 + dd;
    float kc[11];
#pragma unroll
    for (int j = 0; j < 11; ++j) kc[j] = kt[j * 1024 + c];

    const int tl0 = tg * 32;
    float w[11];
#pragma unroll
    for (int j = 0; j < 11; ++j) w[j] = vs[dd][3 + tl0 + j];
    float* orow = out + ((size_t)(b * 1024 + t0 + tl0)) * 1024 + c;
#pragma unroll 4
    for (int s = 0; s < 32; ++s) {
        float acc = 0.f;
#pragma unroll
        for (int j = 0; j < 11; ++j) acc += kc[j] * w[j];
        float mf = ms[8 + tl0 + s];
        orow[(size_t)s * 1024] = (acc + w[5]) * mf;
#pragma unroll
        for (int j = 0; j < 10; ++j) w[j] = w[j + 1];
        w[10] = vs[dd][3 + tl0 + s + 11];
    }
}

// ---------------- attention v2: swapped QK^T, in-register softmax, LDS-free ----------------
__global__ __launch_bounds__(256, 3) void attn_v2(const u16* __restrict__ qg,
                                                  const u16* __restrict__ kg,
                                                  const u16* __restrict__ vtg,
                                                  const uint32_t* __restrict__ mbits,
                                                  u16* __restrict__ ctx)
{
    const int t = threadIdx.x;
    const int lane = t & 63;
    const int w = t >> 6;
    const int lr = lane & 15, lq = lane >> 4;
    const int qc = blockIdx.x & 7;
    const int bh = blockIdx.x >> 3;
    const int b = bh >> 4, h = bh & 15;
    const size_t base = (size_t)bh << 16;
    const u16* kb = kg + base;
    const u16* vb = vtg + base;     // [64][1024]
    const int q0 = qc * 128 + w * 32;

    bf16x8 qf[2][2];
#pragma unroll
    for (int qt = 0; qt < 2; ++qt)
#pragma unroll
        for (int kk = 0; kk < 2; ++kk)
            qf[qt][kk] = *reinterpret_cast<const bf16x8*>(
                qg + base + (size_t)(q0 + qt * 16 + lr) * 64 + kk * 32 + lq * 8);

    f32x4 oacc[2][4];
    float m_[2] = {-1e30f, -1e30f}, l_[2] = {0.f, 0.f};
#pragma unroll
    for (int qt = 0; qt < 2; ++qt)
#pragma unroll
        for (int dt = 0; dt < 4; ++dt) oacc[qt][dt] = (f32x4){0.f, 0.f, 0.f, 0.f};

    const uint32_t* mrow = mbits + b * 32;

    bf16x8 kf[2][2], vf[4];
#pragma unroll
    for (int kt = 0; kt < 2; ++kt)
#pragma unroll
        for (int kk = 0; kk < 2; ++kk)
            kf[kt][kk] = *reinterpret_cast<const bf16x8*>(
                kb + (size_t)(kt * 16 + lr) * 64 + kk * 32 + lq * 8);
#pragma unroll
    for (int dt = 0; dt < 4; ++dt)
        vf[dt] = *reinterpret_cast<const bf16x8*>(vb + (size_t)(dt * 16 + lr) * 1024 + lq * 8);

    for (int it = 0; it < 32; ++it) {
        const int k1 = (it < 31 ? it + 1 : 31) * 32;
        bf16x8 kf_n[2][2], vf_n[4];
#pragma unroll
        for (int kt = 0; kt < 2; ++kt)
#pragma unroll
            for (int kk = 0; kk < 2; ++kk)
                kf_n[kt][kk] = *reinterpret_cast<const bf16x8*>(
                    kb + (size_t)(k1 + kt * 16 + lr) * 64 + kk * 32 + lq * 8);
#pragma unroll
        for (int dt = 0; dt < 4; ++dt)
            vf_n[dt] = *reinterpret_cast<const bf16x8*>(
                vb + (size_t)(dt * 16 + lr) * 1024 + k1 + lq * 8);

        const uint32_t mbit = mrow[it];
        f32x4 ma[2];
#pragma unroll
        for (int kt = 0; kt < 2; ++kt)
#pragma unroll
            for (int r = 0; r < 4; ++r)
                ma[kt][r] = ((mbit >> (kt * 16 + lq * 4 + r)) & 1u) ? 0.f : -3e38f;

        uint32_t pk[2][2][2];
        float alpha[2];
#pragma unroll
        for (int qt = 0; qt < 2; ++qt) {
            f32x4 s0 = (f32x4){0.f, 0.f, 0.f, 0.f};
            f32x4 s1 = (f32x4){0.f, 0.f, 0.f, 0.f};
            s0 = __builtin_amdgcn_mfma_f32_16x16x32_bf16(kf[0][0], qf[qt][0], s0, 0, 0, 0);
            s0 = __builtin_amdgcn_mfma_f32_16x16x32_bf16(kf[0][1], qf[qt][1], s0, 0, 0, 0);
            s1 = __builtin_amdgcn_mfma_f32_16x16x32_bf16(kf[1][0], qf[qt][0], s1, 0, 0, 0);
            s1 = __builtin_amdgcn_mfma_f32_16x16x32_bf16(kf[1][1], qf[qt][1], s1, 0, 0, 0);
            s0 += ma[0]; s1 += ma[1];
            float mx = fmaxf(fmaxf(fmaxf(s0[0], s0[1]), fmaxf(s0[2], s0[3])),
                             fmaxf(fmaxf(s1[0], s1[1]), fmaxf(s1[2], s1[3])));
            mx = fmaxf(mx, __shfl_xor(mx, 16, 64));
            mx = fmaxf(mx, __shfl_xor(mx, 32, 64));
            float mn = fmaxf(m_[qt], mx);
            float al = __expf(m_[qt] - mn);
            m_[qt] = mn;
            float p0 = __expf(s0[0] - mn), p1 = __expf(s0[1] - mn);
            float p2 = __expf(s0[2] - mn), p3 = __expf(s0[3] - mn);
            float p4 = __expf(s1[0] - mn), p5 = __expf(s1[1] - mn);
            float p6 = __expf(s1[2] - mn), p7 = __expf(s1[3] - mn);
            float rs = ((p0 + p1) + (p2 + p3)) + ((p4 + p5) + (p6 + p7));
            rs += __shfl_xor(rs, 16, 64);
            rs += __shfl_xor(rs, 32, 64);
            l_[qt] = l_[qt] * al + rs;
            alpha[qt] = al;
            pk[qt][0][0] = pack_bf16(p0, p1); pk[qt][0][1] = pack_bf16(p2, p3);
            pk[qt][1][0] = pack_bf16(p4, p5); pk[qt][1][1] = pack_bf16(p6, p7);
        }

#pragma unroll
        for (int qt = 0; qt < 2; ++qt) {
            float a0 = __shfl(alpha[qt], 4 * lq + 0, 64);
            float a1 = __shfl(alpha[qt], 4 * lq + 1, 64);
            float a2 = __shfl(alpha[qt], 4 * lq + 2, 64);
            float a3 = __shfl(alpha[qt], 4 * lq + 3, 64);
#pragma unroll
            for (int dt = 0; dt < 4; ++dt) {
                f32x4 o = oacc[qt][dt];
                o[0] *= a0; o[1] *= a1; o[2] *= a2; o[3] *= a3;
                oacc[qt][dt] = o;
            }
        }

        const int srcA = lr + ((lq & 1) << 5);
        const int srcB = srcA + 16;
        const bool selA = (lq < 2);
#pragma unroll
        for (int qt = 0; qt < 2; ++qt) {
            int a0 = __shfl((int)pk[qt][0][0], srcA, 64);
            int a1 = __shfl((int)pk[qt][0][1], srcA, 64);
            int a2 = __shfl((int)pk[qt][0][0], srcB, 64);
            int a3 = __shfl((int)pk[qt][0][1], srcB, 64);
            int b0 = __shfl((int)pk[qt][1][0], srcA, 64);
            int b1 = __shfl((int)pk[qt][1][1], srcA, 64);
            int b2 = __shfl((int)pk[qt][1][0], srcB, 64);
            int b3 = __shfl((int)pk[qt][1][1], srcB, 64);
            union { uint32_t u[4]; bf16x8 v; } afu;
            afu.u[0] = (uint32_t)(selA ? a0 : b0);
            afu.u[1] = (uint32_t)(selA ? a1 : b1);
            afu.u[2] = (uint32_t)(selA ? a2 : b2);
            afu.u[3] = (uint32_t)(selA ? a3 : b3);
#pragma unroll
            for (int dt = 0; dt < 4; ++dt)
                oacc[qt][dt] = __builtin_amdgcn_mfma_f32_16x16x32_bf16(afu.v, vf[dt], oacc[qt][dt], 0, 0, 0);
        }

#pragma unroll
        for (int kt = 0; kt < 2; ++kt)
#pragma unroll
            for (int kk = 0; kk < 2; ++kk) kf[kt][kk] = kf_n[kt][kk];
#pragma unroll
        for (int dt = 0; dt < 4; ++dt) vf[dt] = vf_n[dt];
    }

#pragma unroll
    for (int qt = 0; qt < 2; ++qt) {
        float linv = 1.f / l_[qt];
        float li0 = __shfl(linv, 4 * lq + 0, 64);
        float li1 = __shfl(linv, 4 * lq + 1, 64);
        float li2 = __shfl(linv, 4 * lq + 2, 64);
        float li3 = __shfl(linv, 4 * lq + 3, 64);
        int trow = q0 + qt * 16 + lq * 4;
#pragma unroll
        for (int dt = 0; dt < 4; ++dt) {
            f32x4 o = oacc[qt][dt];
            size_t col = (size_t)h * 64 + dt * 16 + lr;
            ctx[((size_t)(b << 10) + trow + 0) * 1024 + col] = f2bf(o[0] * li0);
            ctx[((size_t)(b << 10) + trow + 1) * 1024 + col] = f2bf(o[1] * li1);
            ctx[((size_t)(b << 10) + trow + 2) * 1024 + col] = f2bf(o[2] * li2);
            ctx[((size_t)(b << 10) + trow + 3) * 1024 + col] = f2bf(o[3] * li3);
        }
    }
}

extern "C" void kernel_launch(void* const* d_in, const int* in_sizes, int n_in,
                              void* d_out, int out_size, void* d_ws, size_t ws_size,
                              hipStream_t stream)
{
    (void)in_sizes; (void)n_in; (void)out_size; (void)ws_size;
    const float* hs   = (const float*)d_in[0];
    const int*   mask = (const int*)d_in[1];
    const float* Wqkv = (const float*)d_in[2];
    const float* bqkv = (const float*)d_in[3];
    const float* Wout = (const float*)d_in[4];
    const float* bout = (const float*)d_in[5];
    const float* fk   = (const float*)d_in[6];
    float* out = (float*)d_out;

    char* ws = (char*)d_ws;
    u16* hsb   = (u16*)(ws);                 // dead after gemm1; reused for mbits/ktT
    u16* wqkvb = (u16*)(ws + 16777216);
    u16* woutb = (u16*)(ws + 23068672);
    u16* qb    = (u16*)(ws + 25165824);      // [B,H,T,64]
    u16* kb    = (u16*)(ws + 41943040);      // [B,H,T,64]
    u16* vtb   = (u16*)(ws + 58720256);      // [B,H,64,T]
    u16* ctxb  = (u16*)(ws + 75497472);      // [B,T,1024]
    uint32_t* mbits = (uint32_t*)ws;         // 1 KB
    float* ktT = (float*)(ws + 4096);        // [11][1024] f32, 45 KB

    cvt_f32_bf16<<<8192, 256, 0, stream>>>(hs,   hsb,   8388608);
    cvt_f32_bf16<<<3072, 256, 0, stream>>>(Wqkv, wqkvb, 3145728);
    cvt_f32_bf16<<<1024, 256, 0, stream>>>(Wout, woutb, 1048576);

    gemm128<0><<<64 * 24, 256, 0, stream>>>(hsb, wqkvb, 8192, 3072, 1024, 24,
                                            bqkv, qb, kb, vtb, nullptr);
    maskbits_kernel<<<1, 256, 0, stream>>>(mask, mbits);
    fsmn_kt<<<44, 256, 0, stream>>>(fk, ktT);
    fsmn_v3<<<1024, 256, 0, stream>>>(vtb, mask, ktT, out);
    attn_v2<<<1024, 256, 0, stream>>>(qb, kb, vtb, mbits, ctxb);
    gemm128<1><<<64 * 8, 256, 0, stream>>>(ctxb, woutb, 8192, 1024, 1024, 8,
                                           bout, nullptr, nullptr, nullptr, out);
}